// Round 2
// baseline (7403.931 us; speedup 1.0000x reference)
//
#include <hip/hip_runtime.h>
#include <hip/hip_bf16.h>

#define HH 51
#define H3 153
#define BPW 8      // batch elements per workgroup
#define BLOCK 512  // 8 waves
#define KP 26      // u32 (f16-pair) words per row: 52 halves, k=51 zero pad

typedef _Float16 h2_t __attribute__((ext_vector_type(2)));

__device__ __forceinline__ float bf2f(unsigned short u) {
    return __uint_as_float(((unsigned)u) << 16);
}

// runtime-dtype load/store: isbf ? bf16 : fp32
__device__ __forceinline__ float loadf(const void* p, size_t idx, bool isbf) {
    return isbf ? bf2f(((const unsigned short*)p)[idx])
                : ((const float*)p)[idx];
}
__device__ __forceinline__ void storef(void* p, size_t idx, float v, bool isbf) {
    if (isbf) ((__hip_bfloat16*)p)[idx] = __float2bfloat16(v);
    else      ((float*)p)[idx] = v;
}

__device__ __forceinline__ float dot2acc(unsigned w, unsigned h, float acc) {
#if __has_builtin(__builtin_amdgcn_fdot2)
    return __builtin_amdgcn_fdot2(__builtin_bit_cast(h2_t, w),
                                  __builtin_bit_cast(h2_t, h), acc, false);
#else
    h2_t a = __builtin_bit_cast(h2_t, w);
    h2_t b = __builtin_bit_cast(h2_t, h);
    acc = fmaf((float)a.x, (float)b.x, acc);
    acc = fmaf((float)a.y, (float)b.y, acc);
    return acc;
#endif
}

// overflow-proof activations: e = exp(-2|v|) in (0,1], never inf
__device__ __forceinline__ float sigm(float v) {
    float e = __expf(-fabsf(v));               // (0,1]
    float s = 1.0f / (1.0f + e);               // sigmoid(|v|) in [0.5,1)
    return (v >= 0.0f) ? s : 1.0f - s;
}
__device__ __forceinline__ float tanh_fast(float v) {
    float e = __expf(-2.0f * fabsf(v));        // (0,1]
    float t = (1.0f - e) / (1.0f + e);         // tanh(|v|)
    return (v >= 0.0f) ? t : -t;
}

__device__ __forceinline__ void dot3(const unsigned* wr, const unsigned* wz, const unsigned* wn,
                                     const unsigned* hh, const unsigned* hl,
                                     float& ar, float& az, float& an) {
#pragma unroll
    for (int kp = 0; kp < KP; ++kp) {
        unsigned hhv = hh[kp], hlv = hl[kp];
        unsigned wrv = wr[kp], wzv = wz[kp], wnv = wn[kp];
        ar = dot2acc(wrv, hhv, ar);
        az = dot2acc(wzv, hhv, az);
        an = dot2acc(wnv, hhv, an);
        ar = dot2acc(wrv, hlv, ar);
        az = dot2acc(wzv, hlv, az);
        an = dot2acc(wnv, hlv, an);
    }
}

__global__ __launch_bounds__(BLOCK) void gru_kernel(
    const void* __restrict__ xg,
    const void* __restrict__ wih1,
    const void* __restrict__ whh1,
    const void* __restrict__ bih1,
    const void* __restrict__ bhh1,
    const void* __restrict__ wih2,
    const void* __restrict__ whh2,
    const void* __restrict__ bih2,
    const void* __restrict__ bhh2,
    const void* __restrict__ wlin,
    const void* __restrict__ blin_p,
    void* __restrict__ dout,
    int T, int TF)
{
    // ---- runtime dtype detection (uniform across all threads/blocks) ----
    // bf16 data: even-index ushorts are small-weight bf16s -> exponent byte
    // in [100,125] for |w| in [~7e-9, 0.25). fp32 data: even-index ushorts
    // are uniform mantissa bits -> P(all 16 in range) ~ 1e-16.
    bool isbf;
    {
        const unsigned short* u = (const unsigned short*)whh1;
        int ok = 1;
#pragma unroll
        for (int k = 0; k < 16; ++k) {
            unsigned e = (u[2 * k] >> 7) & 0xFF;
            ok &= (e >= 100 && e <= 125) ? 1 : 0;
        }
        isbf = (ok != 0);
    }

    // weights packed as f16 pairs (bf16 exact in f16; fp32 rounded to 2^-11 rel)
    __shared__ unsigned wlds[3][H3][KP];      // 0:w_hh1 1:w_hh2 2:w_ih2
    __shared__ unsigned h1pk[2][2][BPW][KP];  // [t-parity][hi/lo][b][kp]
    __shared__ unsigned h2pk[2][BPW][KP];     // [hi/lo][b][kp]
    __shared__ float    xacc[2][BPW];         // ping-pong out accumulator

    const int tid = threadIdx.x;
    const int wv  = tid >> 6, l = tid & 63;
    const int b   = l & 7, ii = l >> 3;
    const int i   = wv + 8 * ii;              // hidden index, balanced across waves
    const bool act = (i < HH);
    const int bg  = blockIdx.x * BPW + b;

    // ---- init LDS ----
    {
        unsigned* hz = &h1pk[0][0][0][0];
        for (int e = tid; e < 2 * 2 * BPW * KP; e += BLOCK) hz[e] = 0u;
        unsigned* hz2 = &h2pk[0][0][0];
        for (int e = tid; e < 2 * BPW * KP; e += BLOCK) hz2[e] = 0u;
        if (tid < 16) xacc[tid >> 3][tid & 7] = 0.0f;
        const void* gw[3] = { whh1, whh2, wih2 };
        for (int e = tid; e < 3 * H3 * KP; e += BLOCK) {
            int m = e / (H3 * KP), r = e % (H3 * KP);
            int j = r / KP, kp = r % KP;
            int k0 = 2 * kp;
            float f0 = (k0 < HH)     ? loadf(gw[m], (size_t)j * HH + k0, isbf)     : 0.0f;
            float f1 = (k0 + 1 < HH) ? loadf(gw[m], (size_t)j * HH + k0 + 1, isbf) : 0.0f;
            h2_t p; p.x = (_Float16)f0; p.y = (_Float16)f1;
            wlds[m][j][kp] = __builtin_bit_cast(unsigned, p);
        }
    }

    // per-thread constants (biases folded)
    float wi1r = 0, wi1z = 0, wi1n = 0, c1r = 0, c1z = 0, c1ni = 0, c1nh = 0;
    float c2r = 0, c2z = 0, c2ni = 0, c2nh = 0, wl = 0;
    const float blv = loadf(blin_p, 0, isbf);
    if (act) {
        wi1r = loadf(wih1, i, isbf); wi1z = loadf(wih1, HH + i, isbf); wi1n = loadf(wih1, 2 * HH + i, isbf);
        c1r  = loadf(bih1, i, isbf) + loadf(bhh1, i, isbf);
        c1z  = loadf(bih1, HH + i, isbf) + loadf(bhh1, HH + i, isbf);
        c1ni = loadf(bih1, 2 * HH + i, isbf); c1nh = loadf(bhh1, 2 * HH + i, isbf);
        c2r  = loadf(bih2, i, isbf) + loadf(bhh2, i, isbf);
        c2z  = loadf(bih2, HH + i, isbf) + loadf(bhh2, HH + i, isbf);
        c2ni = loadf(bih2, 2 * HH + i, isbf); c2nh = loadf(bhh2, 2 * HH + i, isbf);
        wl   = loadf(wlin, i, isbf);
    }
    __syncthreads();

    float h1own = 0.0f, h2own = 0.0f;  // exact fp32 state lives in registers

    for (int t = 0; t < TF; ++t) {
        const int pw = t & 1, pr = pw ^ 1;
        float a2r = 0.f, a2z = 0.f, a2n = 0.f;

        float xv;
        if (t < T) xv = loadf(xg, (size_t)bg * T + t, isbf);
        else       xv = xacc[pr][b] + blv;     // feedback: out(t-1)

        if (t >= 1 && tid < 8)
            storef(dout, (size_t)(blockIdx.x * BPW + tid) * TF + (t - 1),
                   xacc[pr][tid] + blv, isbf);
        if (tid >= 8 && tid < 16) xacc[pw][tid - 8] = 0.0f;

        if (act) {
            // --- phase 1: gh1 (layer1 recurrent) + gh2 (layer2 recurrent) ---
            float ar = c1r, az = c1z, an = c1nh;
            dot3(&wlds[0][i][0], &wlds[0][HH + i][0], &wlds[0][2 * HH + i][0],
                 &h1pk[pr][0][b][0], &h1pk[pr][1][b][0], ar, az, an);
            a2r = c2r; a2z = c2z; a2n = c2nh;
            dot3(&wlds[1][i][0], &wlds[1][HH + i][0], &wlds[1][2 * HH + i][0],
                 &h2pk[0][b][0], &h2pk[1][b][0], a2r, a2z, a2n);

            float r = sigm(ar + xv * wi1r);
            float z = sigm(az + xv * wi1z);
            float n = tanh_fast(fmaf(xv, wi1n, c1ni) + r * an);
            float h1n = n + z * (h1own - n);
            h1own = h1n;
            _Float16 hi = (_Float16)h1n;
            _Float16 lo = (_Float16)(h1n - (float)hi);  // hi+lo ~ fp32 exact
            ((_Float16*)&h1pk[pw][0][b][0])[i] = hi;
            ((_Float16*)&h1pk[pw][1][b][0])[i] = lo;
        }
        __syncthreads();

        float p = 0.0f;
        if (act) {
            // --- phase 2: gi2 = h1_new . w_ih2, combine layer 2 ---
            float in2 = c2ni;
            dot3(&wlds[2][i][0], &wlds[2][HH + i][0], &wlds[2][2 * HH + i][0],
                 &h1pk[pw][0][b][0], &h1pk[pw][1][b][0], a2r, a2z, in2);
            float r2 = sigm(a2r);
            float z2 = sigm(a2z);
            float n2 = tanh_fast(in2 + r2 * a2n);
            float h2n = n2 + z2 * (h2own - n2);
            h2own = h2n;
            _Float16 hi = (_Float16)h2n;
            _Float16 lo = (_Float16)(h2n - (float)hi);
            ((_Float16*)&h2pk[0][b][0])[i] = hi;
            ((_Float16*)&h2pk[1][b][0])[i] = lo;
            p = h2n * wl;
        }
        // out[b] reduction: lanes with same b are l = b + 8*ii
        p += __shfl_xor(p, 8);
        p += __shfl_xor(p, 16);
        p += __shfl_xor(p, 32);
        if (l < 8) atomicAdd(&xacc[pw][b], p);
        __syncthreads();
    }

    if (tid < 8)
        storef(dout, (size_t)(blockIdx.x * BPW + tid) * TF + (TF - 1),
               xacc[(TF - 1) & 1][tid] + blv, isbf);
}

extern "C" void kernel_launch(void* const* d_in, const int* in_sizes, int n_in,
                              void* d_out, int out_size, void* d_ws, size_t ws_size,
                              hipStream_t stream) {
    const int B = 2048;
    const int T = in_sizes[0] / B;   // 1000
    const int TF = out_size / B;     // 2000 (T + future_steps)
    gru_kernel<<<dim3(B / BPW), dim3(BLOCK), 0, stream>>>(
        d_in[0],  // x
        d_in[1],  // w_ih1
        d_in[2],  // w_hh1
        d_in[3],  // b_ih1
        d_in[4],  // b_hh1
        d_in[5],  // w_ih2
        d_in[6],  // w_hh2
        d_in[7],  // b_ih2
        d_in[8],  // b_hh2
        d_in[9],  // w_lin
        d_in[10], // b_lin
        d_out, T, TF);
}